// Round 1
// 2765.231 us; speedup vs baseline: 1.0521x; 1.0521x over previous
//
#include <hip/hip_runtime.h>
#include <stdint.h>

// ---------------------------------------------------------------------------
// SimpleEdgeBlock: two FullyConnectedTensorProducts (64x0e+64x1o)^2 -> same,
// summed. One bf16 MFMA GEMM:
//   rows = 4 per edge (out0, out1_i), N = 64 (w), K = 16384 = p*8192 + v*128
//   + half*64 + u   (v-major K order so y scalars are slab-constant)
// B prepacked bf16 in d_ws in EXACT slab-major LDS order so global_load_lds
// staging is fully coalesced:  B'[slab s][t][oct][w][j], slab = 64 k.
// A (z = x[u]*y[v]) synthesized per 16-k step: x register-cached, y streamed
// per-v through the same DMA queue into a 2KB ping-pong LDS buffer.
// Pipeline: wave-counted s_waitcnt vmcnt(10) + raw s_barrier (no drains).
// ---------------------------------------------------------------------------

typedef __attribute__((ext_vector_type(8))) short short8;   // 8 x bf16 (4 VGPR)
typedef __attribute__((ext_vector_type(16))) float f32x16;  // MFMA 32x32 acc
typedef unsigned short u16;

#define ETOT 100000

__device__ __forceinline__ unsigned pk2(float lo, float hi) {
  // pack hi16(lo), hi16(hi) -> one dword (bf16 truncation; bias cancels in sums)
  return __builtin_amdgcn_perm(__builtin_bit_cast(unsigned, hi),
                               __builtin_bit_cast(unsigned, lo), 0x07060302u);
}
__device__ __forceinline__ void unpk8(short8 s, float f[8]) {
  uint4 u = __builtin_bit_cast(uint4, s);
  unsigned a[4] = {u.x, u.y, u.z, u.w};
#pragma unroll
  for (int jj = 0; jj < 4; ++jj) {
    f[2 * jj]     = __builtin_bit_cast(float, a[jj] << 16);
    f[2 * jj + 1] = __builtin_bit_cast(float, a[jj] & 0xffff0000u);
  }
}
__device__ __forceinline__ short8 scalepack(const float f[8], float ysc) {
  unsigned p0 = pk2(f[0] * ysc, f[1] * ysc);
  unsigned p1 = pk2(f[2] * ysc, f[3] * ysc);
  unsigned p2 = pk2(f[4] * ysc, f[5] * ysc);
  unsigned p3 = pk2(f[6] * ysc, f[7] * ysc);
  uint4 r = make_uint4(p0, p1, p2, p3);
  return __builtin_bit_cast(short8, r);
}
__device__ __forceinline__ short8 pack8(const float f[8]) {
  unsigned p0 = pk2(f[0], f[1]);
  unsigned p1 = pk2(f[2], f[3]);
  unsigned p2 = pk2(f[4], f[5]);
  unsigned p3 = pk2(f[6], f[7]);
  uint4 r = make_uint4(p0, p1, p2, p3);
  return __builtin_bit_cast(short8, r);
}

// async global -> LDS DMA (dest = wave-uniform base + lane*size)
__device__ __forceinline__ void dma16(const void* g, void* l) {
  __builtin_amdgcn_global_load_lds(
      (const __attribute__((address_space(1))) unsigned*)g,
      (__attribute__((address_space(3))) unsigned*)l, 16, 0, 0);
}
__device__ __forceinline__ void dma4(const void* g, void* l) {
  __builtin_amdgcn_global_load_lds(
      (const __attribute__((address_space(1))) unsigned*)g,
      (__attribute__((address_space(3))) unsigned*)l, 4, 0, 0);
}

// ---------------------------------------------------------------------------
// Prep: W (fp32 [u][v][w]) -> B' bf16 in slab-major order:
//   idx = ((((s*2 + t)*8 + oct)*64 + w)*8 + j
//   klin = s*64 + oct*8 + j ; p = klin>>13 ; r = klin&8191
//   v = r>>7 ; half = (r>>6)&1 ; u = r&63
//   t=0: half0 = a0*W_000,       half1 = a0/sqrt3 * W_110
//   t=1: half0 = a1/sqrt3*W_011, half1 = a1/sqrt3 * W_101   (a0==a1)
// ---------------------------------------------------------------------------
__global__ void prep_B(const float* __restrict__ W10, const float* __restrict__ W11,
                       const float* __restrict__ W12, const float* __restrict__ W13,
                       const float* __restrict__ W20, const float* __restrict__ W21,
                       const float* __restrict__ W22, const float* __restrict__ W23,
                       u16* __restrict__ B) {
  int idx = blockIdx.x * 256 + threadIdx.x;  // 2,097,152 total
  int j = idx & 7;
  int w = (idx >> 3) & 63;
  int oct = (idx >> 9) & 7;
  int t = (idx >> 12) & 1;
  int s = idx >> 13;                 // 0..255
  int klin = s * 64 + oct * 8 + j;   // 0..16383
  int p = klin >> 13;
  int r = klin & 8191;
  int v = (r >> 7) & 63;
  int half = (r >> 6) & 1;
  int u = r & 63;
  const float a0 = 0.011048543456039806f;       // 1/sqrt(2*64*64)
  const float a0s3 = a0 * 0.5773502691896258f;  // a0/sqrt(3)
  const float* Wsrc;
  float scale;
  if (t == 0) {
    Wsrc = half ? (p ? W21 : W11) : (p ? W20 : W10);
    scale = half ? a0s3 : a0;
  } else {
    Wsrc = half ? (p ? W23 : W13) : (p ? W22 : W12);
    scale = a0s3;
  }
  float val = Wsrc[u * 4096 + v * 64 + w] * scale;
  unsigned ub = __builtin_bit_cast(unsigned, val);
  ub += 0x7fffu + ((ub >> 16) & 1u);  // RTNE
  B[idx] = (u16)(ub >> 16);
}

// ---------------------------------------------------------------------------
// Main: 128 threads = 2 waves, 64 edges/block (32/wave).
// 256 slabs of 64 k (one half of one v each); shared dbuf B staging via
// global_load_lds; per-v y scalars ride the same DMA queue. No __syncthreads:
// raw s_barrier pairs + uniform s_waitcnt vmcnt(10).
// ---------------------------------------------------------------------------
__global__ __launch_bounds__(128, 2)
void tp_main(const float* __restrict__ e1x, const float* __restrict__ e1y,
             const float* __restrict__ e2x, const float* __restrict__ e2y,
             const u16* __restrict__ B, float* __restrict__ out) {
  __shared__ u16 blds[2][8192];   // [buf][t(2)][oct(8)][w(64)][8]  2 x 16 KB
  __shared__ float yv[2][256];    // [buf][edge(64)][ch(4)]         2 x 1 KB

  const int tid = threadIdx.x;
  const int wv = tid >> 6;
  const int lane = tid & 63;
  const int m = lane & 31;   // MFMA row/col within 32-tile
  const int hw = lane >> 5;  // half-wave -> k-octet select
  const int be0 = blockIdx.x * 64;
  const int e0 = be0 + wv * 32;
  const bool active = (e0 < ETOT);   // ETOT % 32 == 0: active waves are full
  const int e = e0 + m;

  f32x16 acc[4][2] = {};  // [m-tile][n-tile]
  short8 xc[4][4];        // x cache: [ch][u-quarter], ch: x0, x1_0, x1_1, x1_2

  // --- DMA issue helpers (counts MUST stay fixed: 8 B-chunks, 2 y-chunks) ---
  auto issueB = [&](int s1) {  // stage slab s1 into blds[s1&1]; wave's half = t=wv
    const int cb = s1 * 1024 + wv * 512;  // global chunk base
    const u16* src = B + (size_t)(cb + lane) * 8;
    u16* dst = (u16*)&blds[s1 & 1][(wv * 512) * 8];
#pragma unroll
    for (int q = 0; q < 8; ++q) dma16(src + q * 64 * 8, dst + q * 64 * 8);
  };
  auto issueY = [&](int g) {  // y scalars for group g (v = g&63, pair = g>>6)
    const int b2 = g & 1;     // buffer parity from UNclamped g
    if (g > 127) g = 127;     // clamped re-issue keeps vmcnt counts uniform
    const float* Ysrc = (g >> 6) ? e2y : e1y;
    const int v = g & 63;
#pragma unroll
    for (int q = 0; q < 2; ++q) {
      int f = wv * 128 + q * 64 + lane;
      int el = f >> 2, ch = f & 3;
      int eg = be0 + el;
      if (eg > ETOT - 1) eg = ETOT - 1;  // clamp (last block has 32 edges)
      const float* src = Ysrc + (size_t)eg * 256 + (ch == 0 ? v : 64 + v * 3 + (ch - 1));
      dma4(src, &yv[b2][wv * 128 + q * 64]);
    }
  };

  // ---- prologue: queue = [Y(0) x2, B(0) x8] = 10 outstanding ----
  issueY(0);
  issueB(0);

#pragma unroll 1
  for (int p = 0; p < 2; ++p) {
    const float* X = p ? e2x : e1x;

    // ---- gather x into registers (bf16 packed), per lane: its u-slices ----
    if (active) {
#pragma unroll
      for (int q = 0; q < 4; ++q) {  // u = q*16 + hw*8 + j
        const float* px = X + (size_t)e * 256 + q * 16 + hw * 8;
        float4 a4 = *(const float4*)px;
        float4 b4 = *(const float4*)(px + 4);
        float f[8] = {a4.x, a4.y, a4.z, a4.w, b4.x, b4.y, b4.z, b4.w};
        xc[0][q] = pack8(f);
      }
#pragma unroll
      for (int i = 0; i < 3; ++i) {
        const float* px = X + (size_t)e * 256 + 64 + i;
#pragma unroll
        for (int q = 0; q < 4; ++q) {
          float f[8];
#pragma unroll
          for (int j = 0; j < 8; ++j) f[j] = px[(q * 16 + hw * 8 + j) * 3];
          xc[1 + i][q] = pack8(f);
        }
      }
    }

#pragma unroll 1
    for (int sl = 0; sl < 128; ++sl) {
      const int s = p * 128 + sl;  // global slab 0..255
      // issue next slab (+ y for next v-group on even slabs)
      issueB(s + 1 > 255 ? 255 : s + 1);
      if (!(s & 1)) issueY((s >> 1) + 1);
      // steady state: 18(+2) outstanding; keep the 10 newest in flight
      asm volatile("s_waitcnt vmcnt(10)" ::: "memory");
      __builtin_amdgcn_sched_barrier(0);
      __builtin_amdgcn_s_barrier();  // barrier1: slab s fully in LDS (both waves)

      const int h = s & 1;   // half (slab-uniform)
      const int g = s >> 1;  // v-group
      const u16* bb = blds[s & 1];
      if (active) {
        // y scalars for this v, lane's own edge: [y0, y1_0, y1_1, y1_2]
        float4 ysv = *(const float4*)&yv[g & 1][(wv * 32 + m) * 4];
#pragma unroll
        for (int uq = 0; uq < 4; ++uq) {  // 16-k steps within slab
          short8 bfrag[2][2];
#pragma unroll
          for (int tb = 0; tb < 2; ++tb)
#pragma unroll
            for (int n = 0; n < 2; ++n)
              bfrag[tb][n] =
                  *(const short8*)&bb[(tb * 512 + (uq * 2 + hw) * 64 + n * 32 + m) * 8];
          short8 af[4];
          if (h == 0) {  // z = x0[u]*y_b[v]
            float xf[8];
            unpk8(xc[0][uq], xf);
            af[0] = scalepack(xf, ysv.x);
            af[1] = scalepack(xf, ysv.y);
            af[2] = scalepack(xf, ysv.z);
            af[3] = scalepack(xf, ysv.w);
          } else {  // t0: z110 = sum_i x1_i[u]*y1_i[v]; t_i: x1_i[u]*y0[v]
            float x0f[8], x1f[8], x2f[8];
            unpk8(xc[1][uq], x0f);
            unpk8(xc[2][uq], x1f);
            unpk8(xc[3][uq], x2f);
            float z[8];
#pragma unroll
            for (int j = 0; j < 8; ++j)
              z[j] = x0f[j] * ysv.y + x1f[j] * ysv.z + x2f[j] * ysv.w;
            af[0] = pack8(z);
            af[1] = scalepack(x0f, ysv.x);
            af[2] = scalepack(x1f, ysv.x);
            af[3] = scalepack(x2f, ysv.x);
          }
          __builtin_amdgcn_s_setprio(1);
#pragma unroll
          for (int t = 0; t < 4; ++t) {
            const int tb = t ? 1 : 0;
            acc[t][0] = __builtin_amdgcn_mfma_f32_32x32x16_bf16(
                af[t], bfrag[tb][0], acc[t][0], 0, 0, 0);
            acc[t][1] = __builtin_amdgcn_mfma_f32_32x32x16_bf16(
                af[t], bfrag[tb][1], acc[t][1], 0, 0, 0);
          }
          __builtin_amdgcn_s_setprio(0);
        }
      }
      asm volatile("s_waitcnt lgkmcnt(0)" ::: "memory");
      __builtin_amdgcn_sched_barrier(0);
      __builtin_amdgcn_s_barrier();  // barrier2: reads done before buf reuse
    }
  }

  // ---- epilogue: C/D layout col=lane&31, row=(reg&3)+8*(reg>>2)+4*hw ----
  if (active) {
#pragma unroll
    for (int t = 0; t < 4; ++t)
#pragma unroll
      for (int n0 = 0; n0 < 2; ++n0) {
        f32x16 c = acc[t][n0];
        int n = n0 * 32 + m;  // w index
#pragma unroll
        for (int r = 0; r < 16; ++r) {
          int row = (r & 3) + 8 * (r >> 2) + 4 * hw;
          int ee = e0 + row;
          size_t off;
          if (t == 0) off = (size_t)ee * 256 + n;                     // out0[w]
          else        off = (size_t)ee * 256 + 64 + n * 3 + (t - 1);  // out1[w][i]
          out[off] = c[r];
        }
      }
  }
}

extern "C" void kernel_launch(void* const* d_in, const int* in_sizes, int n_in,
                              void* d_out, int out_size, void* d_ws, size_t ws_size,
                              hipStream_t stream) {
  const float* e1x = (const float*)d_in[0];
  const float* e1y = (const float*)d_in[1];
  const float* e2x = (const float*)d_in[2];
  const float* e2y = (const float*)d_in[3];
  const size_t bElems = (size_t)2 * 64 * 16384;  // 2 MiElems bf16 = 4 MiB
  if (ws_size < bElems * sizeof(u16)) return;    // visible as absmax failure
  u16* B = (u16*)d_ws;
  prep_B<<<8192, 256, 0, stream>>>(
      (const float*)d_in[4], (const float*)d_in[5], (const float*)d_in[6],
      (const float*)d_in[7], (const float*)d_in[8], (const float*)d_in[9],
      (const float*)d_in[10], (const float*)d_in[11], B);
  tp_main<<<(ETOT + 63) / 64, 128, 0, stream>>>(e1x, e1y, e2x, e2y, B,
                                                (float*)d_out);
}

// Round 2
// 2636.742 us; speedup vs baseline: 1.1034x; 1.0487x over previous
//
#include <hip/hip_runtime.h>
#include <stdint.h>

// ---------------------------------------------------------------------------
// SimpleEdgeBlock: two FullyConnectedTensorProducts (64x0e+64x1o)^2 -> same,
// summed. One bf16 MFMA GEMM:
//   rows = 4 per edge (out0, out1_i), N = 64 (w), K = 16384 = p*8192 + v*128
//   + half*64 + u   (v-major K order so y scalars are slab-constant)
// B prepacked bf16 in d_ws in EXACT slab-major LDS order so global_load_lds
// staging is fully coalesced:  B'[slab s][t][oct][w][j], slab = 64 k.
// A (z = x[u]*y[v]) synthesized per 16-k step: x register-cached, y streamed
// per-v through the same DMA queue into a ping-pong LDS buffer.
//
// Round-2 change: 4 waves / 128 edges per block (was 2 waves / 64). The
// staged 16 KB slab now feeds 4 waves -> total B re-read traffic halves
// (6.4 GB -> 3.2 GB); this kernel was B-bandwidth-bound (FETCH 4.66 GB at
// ~1.9 TB/s). Per-wave DMA duty: 4 dma16 + 1 dma4 per slab, vmcnt(5).
// ---------------------------------------------------------------------------

typedef __attribute__((ext_vector_type(8))) short short8;   // 8 x bf16 (4 VGPR)
typedef __attribute__((ext_vector_type(16))) float f32x16;  // MFMA 32x32 acc
typedef unsigned short u16;

#define ETOT 100000

__device__ __forceinline__ unsigned pk2(float lo, float hi) {
  // pack hi16(lo), hi16(hi) -> one dword (bf16 truncation; bias cancels in sums)
  return __builtin_amdgcn_perm(__builtin_bit_cast(unsigned, hi),
                               __builtin_bit_cast(unsigned, lo), 0x07060302u);
}
__device__ __forceinline__ void unpk8(short8 s, float f[8]) {
  uint4 u = __builtin_bit_cast(uint4, s);
  unsigned a[4] = {u.x, u.y, u.z, u.w};
#pragma unroll
  for (int jj = 0; jj < 4; ++jj) {
    f[2 * jj]     = __builtin_bit_cast(float, a[jj] << 16);
    f[2 * jj + 1] = __builtin_bit_cast(float, a[jj] & 0xffff0000u);
  }
}
__device__ __forceinline__ short8 scalepack(const float f[8], float ysc) {
  unsigned p0 = pk2(f[0] * ysc, f[1] * ysc);
  unsigned p1 = pk2(f[2] * ysc, f[3] * ysc);
  unsigned p2 = pk2(f[4] * ysc, f[5] * ysc);
  unsigned p3 = pk2(f[6] * ysc, f[7] * ysc);
  uint4 r = make_uint4(p0, p1, p2, p3);
  return __builtin_bit_cast(short8, r);
}
__device__ __forceinline__ short8 pack8(const float f[8]) {
  unsigned p0 = pk2(f[0], f[1]);
  unsigned p1 = pk2(f[2], f[3]);
  unsigned p2 = pk2(f[4], f[5]);
  unsigned p3 = pk2(f[6], f[7]);
  uint4 r = make_uint4(p0, p1, p2, p3);
  return __builtin_bit_cast(short8, r);
}

// async global -> LDS DMA (dest = wave-uniform base + lane*size)
__device__ __forceinline__ void dma16(const void* g, void* l) {
  __builtin_amdgcn_global_load_lds(
      (const __attribute__((address_space(1))) unsigned*)g,
      (__attribute__((address_space(3))) unsigned*)l, 16, 0, 0);
}
__device__ __forceinline__ void dma4(const void* g, void* l) {
  __builtin_amdgcn_global_load_lds(
      (const __attribute__((address_space(1))) unsigned*)g,
      (__attribute__((address_space(3))) unsigned*)l, 4, 0, 0);
}

// ---------------------------------------------------------------------------
// Prep: W (fp32 [u][v][w]) -> B' bf16 in slab-major order:
//   idx = ((((s*2 + t)*8 + oct)*64 + w)*8 + j
//   klin = s*64 + oct*8 + j ; p = klin>>13 ; r = klin&8191
//   v = r>>7 ; half = (r>>6)&1 ; u = r&63
//   t=0: half0 = a0*W_000,       half1 = a0/sqrt3 * W_110
//   t=1: half0 = a1/sqrt3*W_011, half1 = a1/sqrt3 * W_101   (a0==a1)
// ---------------------------------------------------------------------------
__global__ void prep_B(const float* __restrict__ W10, const float* __restrict__ W11,
                       const float* __restrict__ W12, const float* __restrict__ W13,
                       const float* __restrict__ W20, const float* __restrict__ W21,
                       const float* __restrict__ W22, const float* __restrict__ W23,
                       u16* __restrict__ B) {
  int idx = blockIdx.x * 256 + threadIdx.x;  // 2,097,152 total
  int j = idx & 7;
  int w = (idx >> 3) & 63;
  int oct = (idx >> 9) & 7;
  int t = (idx >> 12) & 1;
  int s = idx >> 13;                 // 0..255
  int klin = s * 64 + oct * 8 + j;   // 0..16383
  int p = klin >> 13;
  int r = klin & 8191;
  int v = (r >> 7) & 63;
  int half = (r >> 6) & 1;
  int u = r & 63;
  const float a0 = 0.011048543456039806f;       // 1/sqrt(2*64*64)
  const float a0s3 = a0 * 0.5773502691896258f;  // a0/sqrt(3)
  const float* Wsrc;
  float scale;
  if (t == 0) {
    Wsrc = half ? (p ? W21 : W11) : (p ? W20 : W10);
    scale = half ? a0s3 : a0;
  } else {
    Wsrc = half ? (p ? W23 : W13) : (p ? W22 : W12);
    scale = a0s3;
  }
  float val = Wsrc[u * 4096 + v * 64 + w] * scale;
  unsigned ub = __builtin_bit_cast(unsigned, val);
  ub += 0x7fffu + ((ub >> 16) & 1u);  // RTNE
  B[idx] = (u16)(ub >> 16);
}

// ---------------------------------------------------------------------------
// Main: 256 threads = 4 waves, 128 edges/block (32/wave).
// 256 slabs of 64 k (one half of one v each); shared dbuf B staging via
// global_load_lds split across 4 waves; per-v y scalars ride the same DMA
// queue. Raw s_barrier pairs + uniform s_waitcnt vmcnt(5).
// ---------------------------------------------------------------------------
__global__ __launch_bounds__(256, 2)
void tp_main(const float* __restrict__ e1x, const float* __restrict__ e1y,
             const float* __restrict__ e2x, const float* __restrict__ e2y,
             const u16* __restrict__ B, float* __restrict__ out) {
  __shared__ u16 blds[2][8192];   // [buf][t(2)][oct(8)][w(64)][8]  2 x 16 KB
  __shared__ float yv[2][512];    // [buf][edge(128)][ch(4)]        2 x 2 KB

  const int tid = threadIdx.x;
  const int wv = tid >> 6;   // 0..3
  const int lane = tid & 63;
  const int m = lane & 31;   // MFMA row/col within 32-tile
  const int hw = lane >> 5;  // half-wave -> k-octet select
  const int be0 = blockIdx.x * 128;
  const int e0 = be0 + wv * 32;
  const bool active = (e0 < ETOT);   // ETOT % 32 == 0: active waves are full
  const int e = e0 + m;

  f32x16 acc[4][2] = {};  // [m-tile][n-tile]
  short8 xc[4][4];        // x cache: [ch][u-quarter], ch: x0, x1_0, x1_1, x1_2

  // --- DMA issue helpers (counts MUST stay fixed: 4 B + 1 y per slab) ---
  auto issueB = [&](int s1) {  // wave wv stages chunks wv*4 .. wv*4+3 (1 KB each)
    const int b = s1 & 1;
    const u16* src =
        B + (size_t)s1 * 8192 + (size_t)(wv * 4) * 512 + (size_t)lane * 8;
#pragma unroll
    for (int q = 0; q < 4; ++q)
      dma16(src + q * 512, &blds[b][(wv * 4 + q) * 512]);
  };
  auto issueYhalf = [&](int g, int h) {  // y scalars, half h, group g (v=g&63)
    const int bg = g & 1;                // buffer parity from UNclamped g
    if (g > 127) g = 127;                // clamped re-issue keeps counts uniform
    const float* Ysrc = (g >> 6) ? e2y : e1y;
    const int v = g & 63;
    const int i = h * 4 + wv;   // instruction index 0..7 across block
    const int f = i * 64 + lane;
    const int el = f >> 2, ch = f & 3;
    int eg = be0 + el;
    if (eg > ETOT - 1) eg = ETOT - 1;  // clamp (tail block)
    const float* src =
        Ysrc + (size_t)eg * 256 + (ch == 0 ? v : 64 + v * 3 + (ch - 1));
    dma4(src, &yv[bg][i * 64]);
  };

  // ---- prologue: queue = [Y(0) x2, B(0) x4] = 6 outstanding per wave ----
  issueYhalf(0, 0);
  issueYhalf(0, 1);
  issueB(0);

#pragma unroll 1
  for (int p = 0; p < 2; ++p) {
    const float* X = p ? e2x : e1x;

    // ---- gather x into registers (bf16 packed), per lane: its u-slices ----
    if (active) {
#pragma unroll
      for (int q = 0; q < 4; ++q) {  // u = q*16 + hw*8 + j
        const float* px = X + (size_t)e * 256 + q * 16 + hw * 8;
        float4 a4 = *(const float4*)px;
        float4 b4 = *(const float4*)(px + 4);
        float f[8] = {a4.x, a4.y, a4.z, a4.w, b4.x, b4.y, b4.z, b4.w};
        xc[0][q] = pack8(f);
      }
#pragma unroll
      for (int i = 0; i < 3; ++i) {
        const float* px = X + (size_t)e * 256 + 64 + i;
#pragma unroll
        for (int q = 0; q < 4; ++q) {
          float f[8];
#pragma unroll
          for (int j = 0; j < 8; ++j) f[j] = px[(q * 16 + hw * 8 + j) * 3];
          xc[1 + i][q] = pack8(f);
        }
      }
    }

#pragma unroll 1
    for (int sl = 0; sl < 128; ++sl) {
      const int s = p * 128 + sl;  // global slab 0..255
      // issue next slab's B + one y half-group (constant counts per slab)
      issueB(s + 1 > 255 ? 255 : s + 1);
      issueYhalf((s >> 1) + 1, s & 1);
      // wait: everything issued at slab s-1 (B(s) + y half) is complete
      asm volatile("s_waitcnt vmcnt(5)" ::: "memory");
      __builtin_amdgcn_sched_barrier(0);
      __builtin_amdgcn_s_barrier();  // barrier1: slab s fully in LDS (all waves)

      const int h = s & 1;   // half (slab-uniform)
      const int g = s >> 1;  // v-group
      const u16* bb = blds[s & 1];
      if (active) {
        // y scalars for this v, lane's own edge: [y0, y1_0, y1_1, y1_2]
        float4 ysv = *(const float4*)&yv[g & 1][(wv * 32 + m) * 4];
#pragma unroll
        for (int uq = 0; uq < 4; ++uq) {  // 16-k steps within slab
          short8 bfrag[2][2];
#pragma unroll
          for (int tb = 0; tb < 2; ++tb)
#pragma unroll
            for (int n = 0; n < 2; ++n)
              bfrag[tb][n] =
                  *(const short8*)&bb[(tb * 512 + (uq * 2 + hw) * 64 + n * 32 + m) * 8];
          short8 af[4];
          if (h == 0) {  // z = x0[u]*y_b[v]
            float xf[8];
            unpk8(xc[0][uq], xf);
            af[0] = scalepack(xf, ysv.x);
            af[1] = scalepack(xf, ysv.y);
            af[2] = scalepack(xf, ysv.z);
            af[3] = scalepack(xf, ysv.w);
          } else {  // t0: z110 = sum_i x1_i[u]*y1_i[v]; t_i: x1_i[u]*y0[v]
            float x0f[8], x1f[8], x2f[8];
            unpk8(xc[1][uq], x0f);
            unpk8(xc[2][uq], x1f);
            unpk8(xc[3][uq], x2f);
            float z[8];
#pragma unroll
            for (int j = 0; j < 8; ++j)
              z[j] = x0f[j] * ysv.y + x1f[j] * ysv.z + x2f[j] * ysv.w;
            af[0] = pack8(z);
            af[1] = scalepack(x0f, ysv.x);
            af[2] = scalepack(x1f, ysv.x);
            af[3] = scalepack(x2f, ysv.x);
          }
          __builtin_amdgcn_s_setprio(1);
#pragma unroll
          for (int t = 0; t < 4; ++t) {
            const int tb = t ? 1 : 0;
            acc[t][0] = __builtin_amdgcn_mfma_f32_32x32x16_bf16(
                af[t], bfrag[tb][0], acc[t][0], 0, 0, 0);
            acc[t][1] = __builtin_amdgcn_mfma_f32_32x32x16_bf16(
                af[t], bfrag[tb][1], acc[t][1], 0, 0, 0);
          }
          __builtin_amdgcn_s_setprio(0);
        }
      }
      asm volatile("s_waitcnt lgkmcnt(0)" ::: "memory");
      __builtin_amdgcn_sched_barrier(0);
      __builtin_amdgcn_s_barrier();  // barrier2: reads done before buf reuse
    }
  }

  // ---- epilogue: C/D layout col=lane&31, row=(reg&3)+8*(reg>>2)+4*hw ----
  if (active) {
#pragma unroll
    for (int t = 0; t < 4; ++t)
#pragma unroll
      for (int n0 = 0; n0 < 2; ++n0) {
        f32x16 c = acc[t][n0];
        int n = n0 * 32 + m;  // w index
#pragma unroll
        for (int r = 0; r < 16; ++r) {
          int row = (r & 3) + 8 * (r >> 2) + 4 * hw;
          int ee = e0 + row;
          size_t off;
          if (t == 0) off = (size_t)ee * 256 + n;                     // out0[w]
          else        off = (size_t)ee * 256 + 64 + n * 3 + (t - 1);  // out1[w][i]
          out[off] = c[r];
        }
      }
  }
}

extern "C" void kernel_launch(void* const* d_in, const int* in_sizes, int n_in,
                              void* d_out, int out_size, void* d_ws, size_t ws_size,
                              hipStream_t stream) {
  const float* e1x = (const float*)d_in[0];
  const float* e1y = (const float*)d_in[1];
  const float* e2x = (const float*)d_in[2];
  const float* e2y = (const float*)d_in[3];
  const size_t bElems = (size_t)2 * 64 * 16384;  // 2 MiElems bf16 = 4 MiB
  if (ws_size < bElems * sizeof(u16)) return;    // visible as absmax failure
  u16* B = (u16*)d_ws;
  prep_B<<<8192, 256, 0, stream>>>(
      (const float*)d_in[4], (const float*)d_in[5], (const float*)d_in[6],
      (const float*)d_in[7], (const float*)d_in[8], (const float*)d_in[9],
      (const float*)d_in[10], (const float*)d_in[11], B);
  tp_main<<<(ETOT + 127) / 128, 256, 0, stream>>>(e1x, e1y, e2x, e2y, B,
                                                  (float*)d_out);
}